// Round 4
// baseline (287.673 us; speedup 1.0000x reference)
//
#include <hip/hip_runtime.h>

// LinearAttention, fp16-MFMA (round 4).
//   xT   = transpose+cvt(x)          [b][l][c] f16   (B-operand for K1,K5)
//   kv   = wkvT @ xT^T  (MFMA)       [b][f][l] f16; k-half stored as exp(k),
//                                    per-row Z accumulated via atomics
//   ctxP = v ek^T partials (MFMA, K split 16)  [s][bh][e*64+d] f32
//   a2tT = ((sum_s ctxP)*diag(1/Z) . w_out)^T  [b][c][g] f16
//   Mf   = a2tT @ wqs^T (MFMA)       [b][c][c'] f16
//   out  = Mf @ xT^T + b_out (MFMA, fp32 out)
// Round-4 changes:
//  (a) XOR bank swizzle on LDS tiles (global-side swizzle so global_load_lds
//      stays lane-contiguous): kills the 4 cyc/ds_read_b128 conflict tax.
//  (b) softmax pass eliminated: exp fused into K1 epilogue + Z atomics;
//      1/Z folded into a2t column load (deferred normalization).

typedef _Float16 half2_t __attribute__((ext_vector_type(2)));
typedef _Float16 half4_t __attribute__((ext_vector_type(4)));
typedef _Float16 half8_t __attribute__((ext_vector_type(8)));
typedef float    floatx4 __attribute__((ext_vector_type(4)));

#define SCALE_ 0.125f
#define CSPLIT 16

__device__ __forceinline__ void async_lds16(const _Float16* g, _Float16* l) {
    __builtin_amdgcn_global_load_lds(
        (const __attribute__((address_space(1))) void*)g,
        (__attribute__((address_space(3))) void*)l,
        16, 0, 0);
}

// ---------------- MFMA GEMM: C[m][n] = sum_k A[m][k] * B[n][k] (+bias[m]) ---
// A: [M][K] f16 k-fast. B: [N][K] f16 k-fast. C: [M][N].
// 128x128 tile, BK=32, 4 waves, 16x16x32_f16, global_load_lds width 16.
// LDS tiles XOR-swizzled: LDS[row][chunk s] holds global chunk s^(row&3).
// If zsum != nullptr and m0 < 512: store exp(acc), atomicAdd row sums to zsum.
template <typename OutT>
__global__ __launch_bounds__(256)
void gemm_mfma(const _Float16* __restrict__ A, long aBatch, int K,
               const _Float16* __restrict__ B, long bBatch,
               OutT* __restrict__ C, int ldc, long cBatch,
               const float* __restrict__ bias, float* __restrict__ zsum)
{
    __shared__ _Float16 As[128 * 32];
    __shared__ _Float16 Bs[128 * 32];
    const int tid  = threadIdx.x;
    const int lane = tid & 63;
    const int wave = tid >> 6;
    const int m0 = blockIdx.y * 128;
    const int n0 = blockIdx.x * 128;
    const long bz = blockIdx.z;
    const _Float16* Ag = A + bz * aBatch + (long)m0 * K;
    const _Float16* Bg = B + bz * bBatch + (long)n0 * K;

    // staging: thread t -> row t>>2, global chunk (t&3)^(row&3) (swizzle)
    const int sr = tid >> 2;
    const int sc = (((tid & 3) ^ (sr & 3))) * 8;

    const int wm = (wave & 1) * 64;
    const int wn = (wave >> 1) * 64;
    const int fm = lane & 15;               // fragment m / n
    const int fc = lane >> 4;               // desired k-chunk 0..3
    const int fo = (fc ^ (fm & 3)) * 8;     // swizzled LDS k-offset (halfs)

    floatx4 acc[4][4];
#pragma unroll
    for (int i = 0; i < 4; ++i)
#pragma unroll
        for (int j = 0; j < 4; ++j) acc[i][j] = (floatx4)0.0f;

    for (int k0 = 0; k0 < K; k0 += 32) {
        __syncthreads();                       // prev iter's ds_reads done
        async_lds16(Ag + (long)sr * K + k0 + sc,        &As[tid * 8]);
        async_lds16(Ag + (long)(sr + 64) * K + k0 + sc, &As[2048 + tid * 8]);
        async_lds16(Bg + (long)sr * K + k0 + sc,        &Bs[tid * 8]);
        async_lds16(Bg + (long)(sr + 64) * K + k0 + sc, &Bs[2048 + tid * 8]);
        __syncthreads();                       // vmcnt(0) drain + barrier

        half8_t a[4], b[4];
#pragma unroll
        for (int i = 0; i < 4; ++i)
            a[i] = *(const half8_t*)&As[(wm + i * 16 + fm) * 32 + fo];
#pragma unroll
        for (int j = 0; j < 4; ++j)
            b[j] = *(const half8_t*)&Bs[(wn + j * 16 + fm) * 32 + fo];
#pragma unroll
        for (int i = 0; i < 4; ++i)
#pragma unroll
            for (int j = 0; j < 4; ++j)
                acc[i][j] = __builtin_amdgcn_mfma_f32_16x16x32_f16(
                    a[i], b[j], acc[i][j], 0, 0, 0);
    }

    // C/D layout: n = lane&15, m = (lane>>4)*4 + reg   [m89/m91-verified]
    const int em = (lane >> 4) * 4;
    const int en = lane & 15;

    if (zsum != nullptr && m0 < 512) {
        // k-half: exponentiate + accumulate row sums (softmax deferred)
        float* Zb = zsum + bz * 512;
#pragma unroll
        for (int i = 0; i < 4; ++i) {
#pragma unroll
            for (int r = 0; r < 4; ++r) {
                float rs = 0.0f;
#pragma unroll
                for (int j = 0; j < 4; ++j) {
                    const float e = __expf(acc[i][j][r]);
                    acc[i][j][r] = e;
                    rs += e;
                }
                rs += __shfl_xor(rs, 1);
                rs += __shfl_xor(rs, 2);
                rs += __shfl_xor(rs, 4);
                rs += __shfl_xor(rs, 8);
                if (en == 0)
                    atomicAdd(&Zb[m0 + wm + i * 16 + em + r], rs);
            }
        }
    }

    OutT* Cb = C + bz * cBatch;
#pragma unroll
    for (int i = 0; i < 4; ++i) {
#pragma unroll
        for (int r = 0; r < 4; ++r) {
            const int m = m0 + wm + i * 16 + em + r;
            const float bi = bias ? bias[m] : 0.0f;
#pragma unroll
            for (int j = 0; j < 4; ++j) {
                const int n = n0 + wn + j * 16 + en;
                Cb[(long)m * ldc + n] = (OutT)(acc[i][j][r] + bi);
            }
        }
    }
}

// ---------------- context via MFMA: ctxP[s][bh][e*64+d] --------------------
// Per (bh, slab s): C[m=e][n=d] = sum_l v[e,l] ek[d,l] over slab's 256 l's.
__global__ __launch_bounds__(256)
void context_mfma(const _Float16* __restrict__ kv, float* __restrict__ ctxP)
{
    const int bh = blockIdx.y;             // 0..63
    const int b = bh >> 3, h = bh & 7;
    const int l0 = blockIdx.x * (4096 / CSPLIT);   // 256-wide l slab
    const _Float16* vbase = kv + (long)b * 4194304 + (long)(512 + h * 64) * 4096;
    const _Float16* kbase = kv + (long)b * 4194304 + (long)(h * 64) * 4096;

    __shared__ _Float16 As[64 * 32];   // v tile [e][32]
    __shared__ _Float16 Bs[64 * 32];   // ek tile [d][32]
    const int tid  = threadIdx.x;
    const int lane = tid & 63;
    const int wave = tid >> 6;
    const int sr = tid >> 2;           // 0..63
    const int sc = (((tid & 3) ^ (sr & 3))) * 8;   // swizzled
    const int wm = (wave & 1) * 32;
    const int wn = (wave >> 1) * 32;
    const int fm = lane & 15;
    const int fc = lane >> 4;
    const int fo = (fc ^ (fm & 3)) * 8;

    floatx4 acc[2][2];
#pragma unroll
    for (int i = 0; i < 2; ++i)
#pragma unroll
        for (int j = 0; j < 2; ++j) acc[i][j] = (floatx4)0.0f;

    for (int k0 = 0; k0 < 4096 / CSPLIT; k0 += 32) {
        __syncthreads();
        async_lds16(vbase + (long)sr * 4096 + l0 + k0 + sc, &As[tid * 8]);
        async_lds16(kbase + (long)sr * 4096 + l0 + k0 + sc, &Bs[tid * 8]);
        __syncthreads();

        half8_t a[2], b2[2];
#pragma unroll
        for (int i = 0; i < 2; ++i)
            a[i] = *(const half8_t*)&As[(wm + i * 16 + fm) * 32 + fo];
#pragma unroll
        for (int j = 0; j < 2; ++j)
            b2[j] = *(const half8_t*)&Bs[(wn + j * 16 + fm) * 32 + fo];
#pragma unroll
        for (int i = 0; i < 2; ++i)
#pragma unroll
            for (int j = 0; j < 2; ++j)
                acc[i][j] = __builtin_amdgcn_mfma_f32_16x16x32_f16(
                    a[i], b2[j], acc[i][j], 0, 0, 0);
    }

    const int em = (lane >> 4) * 4;
    const int en = lane & 15;
    float* base = ctxP + ((long)blockIdx.x * 64 + bh) * 4096;
#pragma unroll
    for (int i = 0; i < 2; ++i)
#pragma unroll
        for (int r = 0; r < 4; ++r)
#pragma unroll
            for (int j = 0; j < 2; ++j)
                base[(wm + i * 16 + em + r) * 64 + wn + j * 16 + en] = acc[i][j][r];
}

// ---------------- transpose + fp32->fp16 convert ---------------------------
// src: [R][Cc] fp32 (ld_s). dst: [Cc][R] f16 (ld_d). grid (Cc/64, R/64, batch).
__global__ __launch_bounds__(256)
void transpose_cvt(const float* __restrict__ src, int ld_s, long sB,
                   _Float16* __restrict__ dst, int ld_d, long dB)
{
    __shared__ float tile[64][65];
    const int c0 = blockIdx.x * 64;
    const int r0 = blockIdx.y * 64;
    const float* S = src + (long)blockIdx.z * sB;
    _Float16* D = dst + (long)blockIdx.z * dB;
    const int t = threadIdx.x;
    const int lr = t >> 4;
    const int lc = (t & 15) * 4;
#pragma unroll
    for (int i = 0; i < 4; ++i) {
        const float4 v = *(const float4*)(S + (long)(r0 + lr + 16 * i) * ld_s + c0 + lc);
        tile[lr + 16 * i][lc + 0] = v.x;
        tile[lr + 16 * i][lc + 1] = v.y;
        tile[lr + 16 * i][lc + 2] = v.z;
        tile[lr + 16 * i][lc + 3] = v.w;
    }
    __syncthreads();
    const int rl = (t & 15) * 4;   // dst col base (src row)
    const int cl = t >> 4;         // dst row (src col)
#pragma unroll
    for (int i = 0; i < 4; ++i) {
        const int c = cl + 16 * i;
        half4_t o;
        o[0] = (_Float16)tile[rl + 0][c];
        o[1] = (_Float16)tile[rl + 1][c];
        o[2] = (_Float16)tile[rl + 2][c];
        o[3] = (_Float16)tile[rl + 3][c];
        *(half4_t*)(D + (long)(c0 + c) * ld_d + r0 + rl) = o;
    }
}

// ---------------- wqs[c'][g] = SCALE * w_qkv[c'][g], f16 -------------------
__global__ __launch_bounds__(256)
void scale_wq_kernel(const float* __restrict__ w_qkv, _Float16* __restrict__ wqs)
{
    const int c = blockIdx.x;
    const int t = threadIdx.x;
    const float2 v = *(const float2*)(w_qkv + (long)c * 1536 + t * 2);
    half2_t o;
    o[0] = (_Float16)(v.x * SCALE_);
    o[1] = (_Float16)(v.y * SCALE_);
    *(half2_t*)(wqs + (long)c * 512 + t * 2) = o;
}

// ---- a2tT[b][c][g] = ((sum_s ctxP)*diag(1/Z) . w_out[(h,e),c])^T, f16 -----
// output layout [b][c][g], g fast (k-fast operand for the M-build MFMA)
__global__ __launch_bounds__(256)
void a2t_kernel(const float* __restrict__ ctxP, const float* __restrict__ w_out,
                const float* __restrict__ zsum, _Float16* __restrict__ a2tT)
{
    const int ct = blockIdx.x, h = blockIdx.y, b = blockIdx.z;
    __shared__ float cs[64][64];      // cs[e][d], softmax-normalized
    __shared__ float wsh[64][128];    // wsh[e][c]
    __shared__ _Float16 so[128][64];  // so[c_local][d]
    const int tid = threadIdx.x;
    {
        const int lr = tid >> 4, lc4 = (tid & 15) * 4;
        floatx4 accv[4];
#pragma unroll
        for (int i = 0; i < 4; ++i) accv[i] = (floatx4)0.0f;
        for (int s = 0; s < CSPLIT; ++s) {
            const float* cbase = ctxP + ((long)s * 64 + b * 8 + h) * 4096;
#pragma unroll
            for (int i = 0; i < 4; ++i)
                accv[i] += *(const floatx4*)(cbase + (lr + 16 * i) * 64 + lc4);
        }
        // deferred softmax normalization: scale column d by 1/Z[b][h*64+d]
        const float4 zr = *(const float4*)(zsum + (long)b * 512 + h * 64 + lc4);
        floatx4 iz;
        iz[0] = 1.0f / zr.x; iz[1] = 1.0f / zr.y;
        iz[2] = 1.0f / zr.z; iz[3] = 1.0f / zr.w;
#pragma unroll
        for (int i = 0; i < 4; ++i)
            *(floatx4*)&cs[lr + 16 * i][lc4] = accv[i] * iz;

        const float* wbase = w_out + (long)(h * 64) * 512 + ct * 128;
        const int wr = tid >> 5, wc4 = (tid & 31) * 4;
#pragma unroll
        for (int i = 0; i < 8; ++i) {
            const int e = wr + 8 * i;
            *(float4*)&wsh[e][wc4] = *(const float4*)(wbase + (long)e * 512 + wc4);
        }
    }
    __syncthreads();
    const int tx = tid & 15, ty = tid >> 4;   // c: tx*8+j, d: ty*4+i
    float acc[4][8] = {};
    for (int e = 0; e < 64; ++e) {
        float a[4], bv[8];
#pragma unroll
        for (int i = 0; i < 4; ++i) a[i] = cs[e][ty * 4 + i];
#pragma unroll
        for (int j = 0; j < 8; ++j) bv[j] = wsh[e][tx * 8 + j];
#pragma unroll
        for (int i = 0; i < 4; ++i)
#pragma unroll
            for (int j = 0; j < 8; ++j)
                acc[i][j] = fmaf(a[i], bv[j], acc[i][j]);
    }
#pragma unroll
    for (int i = 0; i < 4; ++i)
#pragma unroll
        for (int j = 0; j < 8; ++j)
            so[tx * 8 + j][ty * 4 + i] = (_Float16)acc[i][j];
    __syncthreads();
    // coalesced f16 write-out: 1024 chunks of 8 halfs
#pragma unroll
    for (int q = tid; q < 1024; q += 256) {
        const int c_local = q >> 3, co = (q & 7) * 8;
        *(half8_t*)(a2tT + (long)b * 262144 + (long)(ct * 128 + c_local) * 512
                    + h * 64 + co) = *(const half8_t*)&so[c_local][co];
    }
}

extern "C" void kernel_launch(void* const* d_in, const int* in_sizes, int n_in,
                              void* d_out, int out_size, void* d_ws, size_t ws_size,
                              hipStream_t stream)
{
    const float* x      = (const float*)d_in[0];   // (8,512,4096)
    const float* w_qkv  = (const float*)d_in[1];   // (512,1536)
    const float* w_out  = (const float*)d_in[2];   // (512,512)
    const float* b_out  = (const float*)d_in[3];   // (512,)
    float* out = (float*)d_out;                    // (8,512,4096)

    char* wsb = (char*)d_ws;                       // ~122 MB total
    _Float16* kv   = (_Float16*)(wsb);             // 64 MB  [b][f][l]
    _Float16* xT   = (_Float16*)(wsb + 67108864);  // 32 MB  [b][l][c]
    _Float16* wkvT = (_Float16*)(wsb + 100663296); // 1 MB   [f][c]
    _Float16* wqs  = (_Float16*)(wsb + 101711872); // 0.5 MB [c'][g]
    _Float16* a2tT = (_Float16*)(wsb + 102236160); // 4 MB   [b][c][g]
    _Float16* mf   = (_Float16*)(wsb + 106430464); // 4 MB   [b][c][c']
    float*    ctxP = (float*)   (wsb + 110624768); // 16 MB  [s][bh][e*64+d]
    float*    zsum = (float*)   (wsb + 127401984); // 16 KB  [b][512]

    // zero the softmax-denominator accumulator (ws is poisoned each call)
    hipMemsetAsync(zsum, 0, 8 * 512 * sizeof(float), stream);

    // xT = transpose+cvt(x): src rows c=512, cols l=4096
    transpose_cvt<<<dim3(64, 8, 8), 256, 0, stream>>>(
        x, 4096, 2097152L, xT, 512, 2097152L);
    // wkvT[f][c]: src rows c=512 (ld 1536, offset 512), cols f=1024
    transpose_cvt<<<dim3(16, 8, 1), 256, 0, stream>>>(
        w_qkv + 512, 1536, 0L, wkvT, 512, 0L);
    // wqs[c'][g] = SCALE * w_qkv[c'][g]
    scale_wq_kernel<<<dim3(512), 256, 0, stream>>>(w_qkv, wqs);

    // K1: kv[b][f][l] = sum_c wkvT[f][c] * xT[b][l][c]
    //     k-half (f<512) stored as exp(k); row sums accumulated into zsum
    gemm_mfma<_Float16><<<dim3(32, 8, 8), 256, 0, stream>>>(
        wkvT, 0L, 512, xT, 2097152L, kv, 4096, 4194304L, nullptr, zsum);

    // K3: context partials via MFMA (reads ek directly; no softmax pass)
    context_mfma<<<dim3(CSPLIT, 64), 256, 0, stream>>>(kv, ctxP);

    // K4a: a2tT (reduces the CSPLIT partials, applies 1/Z on load)
    a2t_kernel<<<dim3(4, 8, 8), 256, 0, stream>>>(ctxP, w_out, zsum, a2tT);

    // K4m: mf[b][c][c'] = sum_g a2tT[b][c][g] * wqs[c'][g]   (= M^T, f16)
    gemm_mfma<_Float16><<<dim3(4, 4, 8), 256, 0, stream>>>(
        a2tT, 262144L, 512, wqs, 0L, mf, 512, 262144L, nullptr, nullptr);

    // K5: out[b][c][l] = sum_c' mf[b][c][c'] * xT[b][l][c'] + b_out[c]
    gemm_mfma<float><<<dim3(32, 4, 8), 256, 0, stream>>>(
        mf, 262144L, 512, xT, 2097152L, out, 4096, 2097152L, b_out, nullptr);
}